// Round 16
// baseline (370.774 us; speedup 1.0000x reference)
//
#include <hip/hip_runtime.h>
#include <math.h>

#define BB 16
#define SS 1024
#define NF 5
#define DD 64
#define HH 8
#define HDIM 8
#define NLAYER 2
#define FFD 128
#define NQ 8
#define QLAY 3
#define NC 3
#define NSWEEP 5
#define BHS_TOT (BB * HH * SS)   // 131072 = 1<<17

typedef __fp16 hf2 __attribute__((ext_vector_type(2)));
__device__ inline hf2 ash2(float f) { union { float f; hf2 h; } u; u.f = f; return u.h; }

// ---------------- embed + positional encoding ----------------
__global__ __launch_bounds__(64) void k_embed(const float* __restrict__ x,
                                              const float* __restrict__ Wemb,
                                              const float* __restrict__ bemb,
                                              float* __restrict__ h) {
    int bs = blockIdx.x;            // 0..B*S-1
    int s  = bs & (SS - 1);
    int d  = threadIdx.x;           // 0..63
    const float* xr = x + bs * NF;
    float acc = bemb[d];
#pragma unroll
    for (int f = 0; f < NF; ++f) acc += xr[f] * Wemb[f * DD + d];
    int i = d >> 1;
    float div = expf((float)(2 * i) * (-9.210340371976184f / 64.0f));
    float ang = (float)s * div;
    float pe = (d & 1) ? cosf(ang) : sinf(ang);
    h[bs * DD + d] = acc + pe;
}

// ---------------- fused q,k,v projection (4 rows/block; f16 packed out) -----
__global__ __launch_bounds__(64) void k_qkv(const float* __restrict__ h,
                                            const float* __restrict__ Wq, const float* __restrict__ bq,
                                            const float* __restrict__ Wk, const float* __restrict__ bk,
                                            const float* __restrict__ Wv, const float* __restrict__ bv,
                                            hf2* __restrict__ qh, hf2* __restrict__ kvh, int l) {
    __shared__ float hrow[4][DD];
    int d   = threadIdx.x;
    int bs0 = blockIdx.x * 4;
#pragma unroll
    for (int r = 0; r < 4; ++r) hrow[r][d] = h[(bs0 + r) * DD + d];
    __syncthreads();
    const float* wq = Wq + l * DD * DD;
    const float* wk = Wk + l * DD * DD;
    const float* wv = Wv + l * DD * DD;
    float aq[4], ak[4], av[4];
    float bqv = bq[l * DD + d], bkv = bk[l * DD + d], bvv = bv[l * DD + d];
#pragma unroll
    for (int r = 0; r < 4; ++r) { aq[r] = bqv; ak[r] = bkv; av[r] = bvv; }
#pragma unroll 4
    for (int i = 0; i < DD; ++i) {
        float wqv = wq[i * DD + d], wkv = wk[i * DD + d], wvv = wv[i * DD + d];
#pragma unroll
        for (int r = 0; r < 4; ++r) {
            float hv = hrow[r][i];
            aq[r] += hv * wqv; ak[r] += hv * wkv; av[r] += hv * wvv;
        }
    }
    int hh = d >> 3, hd = d & 7;
    const float qs = 0.3535533906f;
    float aqp[4], akp[4];
#pragma unroll
    for (int r = 0; r < 4; ++r) { aqp[r] = __shfl_xor(aq[r], 1); akp[r] = __shfl_xor(ak[r], 1); }
    if ((hd & 1) == 0) {
#pragma unroll
        for (int r = 0; r < 4; ++r) {
            int bs = bs0 + r;
            int b = bs >> 10, s = bs & 1023;
            int bh = b * HH + hh;
            int bhs = (bh << 10) | s;
            qh[bhs * 4 + (hd >> 1)] = __builtin_amdgcn_cvt_pkrtz(aq[r] * qs, aqp[r] * qs);
            int tp = s >> 1, par = s & 1;
            kvh[(bh * 512 + tp) * 16 + par * 4 + (hd >> 1)] =
                __builtin_amdgcn_cvt_pkrtz(ak[r], akp[r]);
        }
    }
#pragma unroll
    for (int r = 0; r < 4; r += 2) {
        int bs = bs0 + r;
        int b = bs >> 10, s = bs & 1023;
        int bh = b * HH + hh;
        int tp = s >> 1;
        kvh[(bh * 512 + tp) * 16 + 8 + hd] = __builtin_amdgcn_cvt_pkrtz(av[r], av[r + 1]);
    }
}

// ---------------- attention: f16 dot2, kv in LDS, 2 rows/thread -------------
// Rows s and s+512 share every KV read (LDS-issue was the binding pipe).
__global__ __launch_bounds__(256) void k_attn(const hf2* __restrict__ qh,
                                              const float4* __restrict__ kvh4,
                                              float* __restrict__ Apart,   // [nch][BHS][8]
                                              float* __restrict__ lpart,   // [nch][BHS]
                                              int nch) {
    __shared__ float4 KVs[1024];      // up to 16 KB (tpc<=256)
    int bh  = blockIdx.x;             // 0..127
    int sg  = blockIdx.y & 1;
    int ch  = blockIdx.y >> 1;
    int tid = threadIdx.x;
    int s0  = sg * 256 + tid;
    int s1  = s0 + 512;
    int tpc = 512 / nch;              // t-pairs per chunk
    const float4* kp = kvh4 + (size_t)(bh * 512 + ch * tpc) * 4;
    for (int i = tid; i < tpc * 4; i += 256) KVs[i] = kp[i];
    float4 qv0 = ((const float4*)qh)[(bh << 10) | s0];
    float4 qv1 = ((const float4*)qh)[(bh << 10) | s1];
    hf2 a01 = ash2(qv0.x), a23 = ash2(qv0.y), a45 = ash2(qv0.z), a67 = ash2(qv0.w);
    hf2 b01 = ash2(qv1.x), b23 = ash2(qv1.y), b45 = ash2(qv1.z), b67 = ash2(qv1.w);
    hf2 one2 = __builtin_amdgcn_cvt_pkrtz(1.f, 1.f);
    float ls0 = 0.f, ls1 = 0.f;
    float A0[8] = {0,0,0,0,0,0,0,0}, A1[8] = {0,0,0,0,0,0,0,0};
    __syncthreads();
#pragma unroll 2
    for (int t = 0; t < tpc; ++t) {
        float4 f0 = KVs[4*t], f1 = KVs[4*t+1], f2 = KVs[4*t+2], f3 = KVs[4*t+3];
        hf2 k00 = ash2(f0.x), k01 = ash2(f0.y), k02 = ash2(f0.z), k03 = ash2(f0.w);
        hf2 k10 = ash2(f1.x), k11 = ash2(f1.y), k12 = ash2(f1.z), k13 = ash2(f1.w);
        float scA0 = __builtin_amdgcn_fdot2(a67, k03,
                     __builtin_amdgcn_fdot2(a45, k02,
                     __builtin_amdgcn_fdot2(a23, k01,
                     __builtin_amdgcn_fdot2(a01, k00, 0.f, false), false), false), false);
        float scA1 = __builtin_amdgcn_fdot2(a67, k13,
                     __builtin_amdgcn_fdot2(a45, k12,
                     __builtin_amdgcn_fdot2(a23, k11,
                     __builtin_amdgcn_fdot2(a01, k10, 0.f, false), false), false), false);
        float scB0 = __builtin_amdgcn_fdot2(b67, k03,
                     __builtin_amdgcn_fdot2(b45, k02,
                     __builtin_amdgcn_fdot2(b23, k01,
                     __builtin_amdgcn_fdot2(b01, k00, 0.f, false), false), false), false);
        float scB1 = __builtin_amdgcn_fdot2(b67, k13,
                     __builtin_amdgcn_fdot2(b45, k12,
                     __builtin_amdgcn_fdot2(b23, k11,
                     __builtin_amdgcn_fdot2(b01, k10, 0.f, false), false), false), false);
        hf2 pA = __builtin_amdgcn_cvt_pkrtz(__expf(scA0), __expf(scA1));
        hf2 pB = __builtin_amdgcn_cvt_pkrtz(__expf(scB0), __expf(scB1));
        hf2 v0 = ash2(f2.x), v1 = ash2(f2.y), v2 = ash2(f2.z), v3 = ash2(f2.w);
        hf2 v4 = ash2(f3.x), v5 = ash2(f3.y), v6 = ash2(f3.z), v7 = ash2(f3.w);
        ls0   = __builtin_amdgcn_fdot2(pA, one2, ls0, false);
        ls1   = __builtin_amdgcn_fdot2(pB, one2, ls1, false);
        A0[0] = __builtin_amdgcn_fdot2(pA, v0, A0[0], false);
        A0[1] = __builtin_amdgcn_fdot2(pA, v1, A0[1], false);
        A0[2] = __builtin_amdgcn_fdot2(pA, v2, A0[2], false);
        A0[3] = __builtin_amdgcn_fdot2(pA, v3, A0[3], false);
        A0[4] = __builtin_amdgcn_fdot2(pA, v4, A0[4], false);
        A0[5] = __builtin_amdgcn_fdot2(pA, v5, A0[5], false);
        A0[6] = __builtin_amdgcn_fdot2(pA, v6, A0[6], false);
        A0[7] = __builtin_amdgcn_fdot2(pA, v7, A0[7], false);
        A1[0] = __builtin_amdgcn_fdot2(pB, v0, A1[0], false);
        A1[1] = __builtin_amdgcn_fdot2(pB, v1, A1[1], false);
        A1[2] = __builtin_amdgcn_fdot2(pB, v2, A1[2], false);
        A1[3] = __builtin_amdgcn_fdot2(pB, v3, A1[3], false);
        A1[4] = __builtin_amdgcn_fdot2(pB, v4, A1[4], false);
        A1[5] = __builtin_amdgcn_fdot2(pB, v5, A1[5], false);
        A1[6] = __builtin_amdgcn_fdot2(pB, v6, A1[6], false);
        A1[7] = __builtin_amdgcn_fdot2(pB, v7, A1[7], false);
    }
    size_t base = ((size_t)ch << 17);
    int bhs0 = (bh << 10) | s0;
    int bhs1 = (bh << 10) | s1;
    float* ar0 = Apart + (base + bhs0) * 8;
    ((float4*)ar0)[0] = make_float4(A0[0], A0[1], A0[2], A0[3]);
    ((float4*)ar0)[1] = make_float4(A0[4], A0[5], A0[6], A0[7]);
    lpart[base + bhs0] = ls0;
    float* ar1 = Apart + (base + bhs1) * 8;
    ((float4*)ar1)[0] = make_float4(A1[0], A1[1], A1[2], A1[3]);
    ((float4*)ar1)[1] = make_float4(A1[4], A1[5], A1[6], A1[7]);
    lpart[base + bhs1] = ls1;
}

// ---------------- attention combine + O projection + residual + layernorm ----
__global__ __launch_bounds__(64) void k_projln(const float* __restrict__ Apart,
                                               const float* __restrict__ lpart,
                                               const float* __restrict__ Wo, const float* __restrict__ bo,
                                               const float* __restrict__ g, const float* __restrict__ bp,
                                               float* __restrict__ h, int l, int nch) {
    __shared__ float orow[4][DD];
    int d   = threadIdx.x;
    int bs0 = blockIdx.x * 4;
    int hh = d >> 3, hd = d & 7;
#pragma unroll
    for (int r = 0; r < 4; ++r) {
        int bs = bs0 + r;
        int b = bs >> 10, s = bs & 1023;
        int bhs = ((b * HH + hh) << 10) | s;
        float a = 0.f, lt = 0.f;
        for (int ch = 0; ch < nch; ++ch) {
            a  += Apart[(((size_t)ch << 17) + bhs) * 8 + hd];
            lt += lpart[((size_t)ch << 17) + bhs];
        }
        orow[r][d] = a / lt;
    }
    __syncthreads();
    const float* w = Wo + l * DD * DD;
    float bias = bo[l * DD + d];
    float acc[4] = {bias, bias, bias, bias};
#pragma unroll 4
    for (int i = 0; i < DD; ++i) {
        float wv = w[i * DD + d];
        acc[0] += orow[0][i]*wv; acc[1] += orow[1][i]*wv;
        acc[2] += orow[2][i]*wv; acc[3] += orow[3][i]*wv;
    }
    float gg = g[l * DD + d], bb = bp[l * DD + d];
#pragma unroll
    for (int r = 0; r < 4; ++r) {
        int bs = bs0 + r;
        float a = acc[r] + h[bs * DD + d];
        float sum = a;
        for (int off = 32; off; off >>= 1) sum += __shfl_xor(sum, off);
        float mean = sum * (1.f / 64.f);
        float dx = a - mean;
        float vs = dx * dx;
        for (int off = 32; off; off >>= 1) vs += __shfl_xor(vs, off);
        float rstd = rsqrtf(vs * (1.f / 64.f) + 1e-5f);
        h[bs * DD + d] = dx * rstd * gg + bb;
    }
}

// ---------------- fused FFN: relu(h W1 + b1) W2 + b2 + residual + LN --------
__global__ __launch_bounds__(128) void k_ffn(const float* __restrict__ Wf1, const float* __restrict__ bf1,
                                             const float* __restrict__ Wf2, const float* __restrict__ bf2,
                                             const float* __restrict__ g, const float* __restrict__ bp,
                                             float* __restrict__ h, int l) {
    __shared__ float hrow[4][DD];
    __shared__ float frow[4][FFD];
    int t   = threadIdx.x;
    int bs0 = blockIdx.x * 4;
#pragma unroll
    for (int e = t; e < 4 * DD; e += 128) ((float*)hrow)[e] = h[bs0 * DD + e];
    __syncthreads();
    {
        const float* w = Wf1 + l * DD * FFD;
        float bv = bf1[l * FFD + t];
        float a0 = bv, a1 = bv, a2 = bv, a3 = bv;
#pragma unroll 4
        for (int i = 0; i < DD; ++i) {
            float wv = w[i * FFD + t];
            a0 += hrow[0][i]*wv; a1 += hrow[1][i]*wv;
            a2 += hrow[2][i]*wv; a3 += hrow[3][i]*wv;
        }
        frow[0][t] = fmaxf(a0, 0.f); frow[1][t] = fmaxf(a1, 0.f);
        frow[2][t] = fmaxf(a2, 0.f); frow[3][t] = fmaxf(a3, 0.f);
    }
    __syncthreads();
    {
        int d = t & 63, half = t >> 6;
        int r0 = half * 2, r1 = r0 + 1;
        const float* w = Wf2 + l * FFD * DD;
        float bias = bf2[l * DD + d];
        float acc0 = bias, acc1 = bias;
#pragma unroll 4
        for (int i = 0; i < FFD; ++i) {
            float wv = w[i * DD + d];
            acc0 += frow[r0][i] * wv;
            acc1 += frow[r1][i] * wv;
        }
        float gg = g[l * DD + d], bb = bp[l * DD + d];
        float accs[2] = {acc0, acc1};
#pragma unroll
        for (int rr = 0; rr < 2; ++rr) {
            int r = r0 + rr;
            float a = accs[rr] + hrow[r][d];
            float sum = a;
            for (int off = 32; off; off >>= 1) sum += __shfl_xor(sum, off);
            float mean = sum * (1.f / 64.f);
            float dx = a - mean;
            float vs = dx * dx;
            for (int off = 32; off; off >>= 1) vs += __shfl_xor(vs, off);
            float rstd = rsqrtf(vs * (1.f / 64.f) + 1e-5f);
            h[(bs0 + r) * DD + d] = dx * rstd * gg + bb;
        }
    }
}

// ---------------- mean pool over sequence (8-way split) ----------------
__global__ __launch_bounds__(64) void k_pool(const float* __restrict__ h, float* __restrict__ pp) {
    int b = blockIdx.x, c = blockIdx.y, d = threadIdx.x;
    const float* hp = h + (b * SS + c * 128) * DD + d;
    float acc = 0.f;
#pragma unroll 8
    for (int s = 0; s < 128; ++s) acc += hp[s * DD];
    pp[(b * 8 + c) * DD + d] = acc;
}

// ---------------- fused tail: head (angles) + quantum circuit + eigensolver -
__global__ __launch_bounds__(64) void k_tail(const float* __restrict__ pp,
                                             const float* __restrict__ Wp1, const float* __restrict__ bp1,
                                             const float* __restrict__ Wp2, const float* __restrict__ bp2,
                                             const float* __restrict__ qw,
                                             float* __restrict__ out) {
    __shared__ float pool_s[DD];
    __shared__ float hid[32];
    __shared__ float ang_s[NQ];
    __shared__ float2 Ps2[256];
    int b = blockIdx.x; int L = threadIdx.x;

    // ---- head ----
    {
        float acc = 0.f;
#pragma unroll
        for (int c = 0; c < 8; ++c) acc += pp[(b * 8 + c) * DD + L];
        pool_s[L] = acc * (1.f / 1024.f);
    }
    __syncthreads();
    if (L < 32) {
        float a = bp1[L];
        for (int i = 0; i < DD; ++i) a += pool_s[i] * Wp1[i * 32 + L];
        hid[L] = fmaxf(a, 0.f);
    }
    __syncthreads();
    if (L < NQ) {
        float a = bp2[L];
        for (int j = 0; j < 32; ++j) a += hid[j] * Wp2[j * NQ + L];
        ang_s[L] = tanhf(a) * 3.14159265358979f;
    }
    __syncthreads();

    // ---- quantum circuit ----
    float ar[4], ai[4];
#pragma unroll
    for (int r = 0; r < 4; ++r) { ar[r] = 0.f; ai[r] = 0.f; }
    if (L == 0) ar[0] = 1.f;

    for (int l = 0; l < QLAY; ++l) {
#pragma unroll
        for (int w = 0; w < NQ; ++w) {
            int p = 7 - w;
            float half = 0.5f * ang_s[w];
            float c = cosf(half), s = sinf(half);
            if (p == 7) {
#pragma unroll
                for (int lo = 0; lo < 2; ++lo) {
                    int hi = lo + 2;
                    float r0=ar[lo], m0=ai[lo], r1=ar[hi], m1=ai[hi];
                    ar[lo] = c*r0 + s*m1;  ai[lo] = c*m0 - s*r1;
                    ar[hi] = c*r1 + s*m0;  ai[hi] = c*m1 - s*r0;
                }
            } else if (p == 6) {
#pragma unroll
                for (int base = 0; base < 4; base += 2) {
                    int lo = base, hi = base + 1;
                    float r0=ar[lo], m0=ai[lo], r1=ar[hi], m1=ai[hi];
                    ar[lo] = c*r0 + s*m1;  ai[lo] = c*m0 - s*r1;
                    ar[hi] = c*r1 + s*m0;  ai[hi] = c*m1 - s*r0;
                }
            } else {
                int mask = 1 << p;
#pragma unroll
                for (int r = 0; r < 4; ++r) {
                    float pre = __shfl_xor(ar[r], mask);
                    float pim = __shfl_xor(ai[r], mask);
                    float nr = c*ar[r] + s*pim;
                    float ni = c*ai[r] - s*pre;
                    ar[r] = nr; ai[r] = ni;
                }
            }
        }
#pragma unroll
        for (int w = 0; w < NQ; ++w) {
            const float* p3 = qw + (l * NQ + w) * 3;
            float phi = p3[0], th = p3[1], om = p3[2];
            float ct = cosf(0.5f * th), st = sinf(0.5f * th);
            float al = 0.5f * (phi + om), be = 0.5f * (phi - om);
            float ca = cosf(al), sa = sinf(al), cb = cosf(be), sb = sinf(be);
            float u00r =  ct * ca, u00i = -ct * sa;
            float u01r = -st * cb, u01i = -st * sb;
            float u10r =  st * cb, u10i = -st * sb;
            float u11r =  ct * ca, u11i =  ct * sa;
            int p = 7 - w;
            if (p >= 6) {
#pragma unroll
                for (int pi_ = 0; pi_ < 2; ++pi_) {
                    int lo = (p == 7) ? pi_ : pi_ * 2;
                    int hi = (p == 7) ? pi_ + 2 : pi_ * 2 + 1;
                    float r0=ar[lo], m0=ai[lo], r1=ar[hi], m1=ai[hi];
                    ar[lo] = u00r*r0 - u00i*m0 + u01r*r1 - u01i*m1;
                    ai[lo] = u00r*m0 + u00i*r0 + u01r*m1 + u01i*r1;
                    ar[hi] = u10r*r0 - u10i*m0 + u11r*r1 - u11i*m1;
                    ai[hi] = u10r*m0 + u10i*r0 + u11r*m1 + u11i*r1;
                }
            } else {
                int mask = 1 << p;
                int bit = (L >> p) & 1;
                float car = bit ? u11r : u00r, cai = bit ? u11i : u00i;
                float cpr = bit ? u10r : u01r, cpi = bit ? u10i : u01i;
#pragma unroll
                for (int r = 0; r < 4; ++r) {
                    float pre = __shfl_xor(ar[r], mask);
                    float pim = __shfl_xor(ai[r], mask);
                    float nr = car*ar[r] - cai*ai[r] + cpr*pre - cpi*pim;
                    float ni = car*ai[r] + cai*ar[r] + cpr*pim + cpi*pre;
                    ar[r] = nr; ai[r] = ni;
                }
            }
        }
        { float t0=ar[2]; ar[2]=ar[3]; ar[3]=t0; t0=ai[2]; ai[2]=ai[3]; ai[3]=t0; }
        ar[1]=__shfl_xor(ar[1],32); ai[1]=__shfl_xor(ai[1],32);
        ar[3]=__shfl_xor(ar[3],32); ai[3]=__shfl_xor(ai[3],32);
#pragma unroll
        for (int w = 2; w <= 6; ++w) {
            int pc = 7 - w, pt = 6 - w;
            int tm = 1 << pt;
            bool ctrl = (L >> pc) & 1;
#pragma unroll
            for (int r = 0; r < 4; ++r) {
                float swr = __shfl_xor(ar[r], tm);
                float swi = __shfl_xor(ai[r], tm);
                ar[r] = ctrl ? swr : ar[r];
                ai[r] = ctrl ? swi : ai[r];
            }
        }
        {
            bool ctrl = L & 1;
            float n0r = ctrl ? ar[2] : ar[0], n2r = ctrl ? ar[0] : ar[2];
            float n0i = ctrl ? ai[2] : ai[0], n2i = ctrl ? ai[0] : ai[2];
            float n1r = ctrl ? ar[3] : ar[1], n3r = ctrl ? ar[1] : ar[3];
            float n1i = ctrl ? ai[3] : ai[1], n3i = ctrl ? ai[1] : ai[3];
            ar[0]=n0r; ar[1]=n1r; ar[2]=n2r; ar[3]=n3r;
            ai[0]=n0i; ai[1]=n1i; ai[2]=n2i; ai[3]=n3i;
        }
    }

    // ---- <Z_w>, w=0..2 ----
    {
        float p0 = ar[0]*ar[0]+ai[0]*ai[0];
        float p1 = ar[1]*ar[1]+ai[1]*ai[1];
        float p2 = ar[2]*ar[2]+ai[2]*ai[2];
        float p3 = ar[3]*ar[3]+ai[3]*ai[3];
        float z0 = p0 + p1 - p2 - p3;
        float z1 = p0 - p1 + p2 - p3;
        float zs = p0 + p1 + p2 + p3;
        float z2 = (L & 32) ? -zs : zs;
#pragma unroll
        for (int off = 1; off < 64; off <<= 1) {
            z0 += __shfl_xor(z0, off);
            z1 += __shfl_xor(z1, off);
            z2 += __shfl_xor(z2, off);
        }
        if (L == 0) {
            out[b * NC + 0] = z0;
            out[b * NC + 1] = z1;
            out[b * NC + 2] = z2;
        }
    }

    // ---- hand off psi through LDS, redistribute to column layout ----
#pragma unroll
    for (int r = 0; r < 4; ++r) Ps2[(r << 6) | L] = make_float2(ar[r], ai[r]);
    __syncthreads();
    int c   = L >> 2;                 // my column
    int seg = L & 3;                  // my segment (4 elements)
    float gr[4], gi[4];
#pragma unroll
    for (int j = 0; j < 4; ++j) {
        float2 t = Ps2[(seg * 4 + j) * 16 + c];
        gr[j] = t.x; gi[j] = t.y;
    }
    float alm = 0.f;
#pragma unroll
    for (int j = 0; j < 4; ++j) alm += gr[j]*gr[j] + gi[j]*gi[j];
    alm += __shfl_xor(alm, 1);
    alm += __shfl_xor(alm, 2);

    // ---- one-sided Jacobi: XOR tournament, shfl_xor exchange ----
    for (int sweep = 0; sweep < NSWEEP; ++sweep) {
#pragma unroll 1
        for (int m = 1; m <= 15; ++m) {
            int xm = m << 2;          // lane xor mask (column bits)
            float pgr[4], pgi[4];
#pragma unroll
            for (int j = 0; j < 4; ++j) {
                pgr[j] = __shfl_xor(gr[j], xm);
                pgi[j] = __shfl_xor(gi[j], xm);
            }
            float bep = __shfl_xor(alm, xm);   // partner norm (same latency group)
            float d = 0.f, e = 0.f;
#pragma unroll
            for (int j = 0; j < 4; ++j) {
                d += gr[j]*pgr[j] + gi[j]*pgi[j];   // Re(mine^H partner)
                e += gr[j]*pgi[j] - gi[j]*pgr[j];   // Im(mine^H partner)
            }
            d += __shfl_xor(d, 1); e += __shfl_xor(e, 1);
            d += __shfl_xor(d, 2); e += __shfl_xor(e, 2);
            float g2 = d*d + e*e;
            float cth = 1.f, sth = 0.f, cph = 1.f, sph = 0.f, gn = 0.f;
            if (g2 > 1e-26f) {
                gn = sqrtf(g2);
                float ginv = 1.f / gn;
                cph = d * ginv; sph = -e * ginv;    // conj(gamma)/|gamma|
                float tau = (alm - bep) * (0.5f * ginv);
                float t = ((tau >= 0.f) ? 1.f : -1.f) / (fabsf(tau) + sqrtf(1.f + tau*tau));
                cth = rsqrtf(1.f + t*t);
                sth = t * cth;
            }
#pragma unroll
            for (int j = 0; j < 4; ++j) {
                float er = cph*pgr[j] - sph*pgi[j];
                float ei = cph*pgi[j] + sph*pgr[j];
                gr[j] = cth * gr[j] + sth * er;
                gi[j] = cth * gi[j] + sth * ei;
            }
            alm = cth*cth*alm + sth*sth*bep + 2.f*cth*sth*gn;
        }
    }

    float ev = fminf(fmaxf(alm, 1e-10f), 1.0f);
    float term = -ev * logf(ev);
#pragma unroll
    for (int off = 4; off < 64; off <<= 1) term += __shfl_xor(term, off);
    if (L == 0) out[BB * NC + b] = term;
}

extern "C" void kernel_launch(void* const* d_in, const int* in_sizes, int n_in,
                              void* d_out, int out_size, void* d_ws, size_t ws_size,
                              hipStream_t stream) {
    const float* x    = (const float*)d_in[0];
    const float* Wemb = (const float*)d_in[1];
    const float* bemb = (const float*)d_in[2];
    const float* Wq   = (const float*)d_in[3];
    const float* bq   = (const float*)d_in[4];
    const float* Wk   = (const float*)d_in[5];
    const float* bk   = (const float*)d_in[6];
    const float* Wv   = (const float*)d_in[7];
    const float* bv   = (const float*)d_in[8];
    const float* Wo   = (const float*)d_in[9];
    const float* bo   = (const float*)d_in[10];
    const float* ln1g = (const float*)d_in[11];
    const float* ln1b = (const float*)d_in[12];
    const float* ln2g = (const float*)d_in[13];
    const float* ln2b = (const float*)d_in[14];
    const float* Wf1  = (const float*)d_in[15];
    const float* bf1  = (const float*)d_in[16];
    const float* Wf2  = (const float*)d_in[17];
    const float* bf2  = (const float*)d_in[18];
    const float* Wp1  = (const float*)d_in[19];
    const float* bp1  = (const float*)d_in[20];
    const float* Wp2  = (const float*)d_in[21];
    const float* bp2  = (const float*)d_in[22];
    const float* qwts = (const float*)d_in[23];
    float* out = (float*)d_out;

    const size_t M = 1u << 20;           // 1M floats = B*S*D
    auto needF = [&](int nch) {
        return (size_t)(4.5 * M) + (size_t)nch * M + (size_t)nch * BHS_TOT + BB * 8 * DD + 16384;
    };
    int nch = (ws_size >= needF(4) * sizeof(float)) ? 4 : 2;

    float* ws     = (float*)d_ws;
    float* h      = ws;                               // 1M
    hf2*   qh     = (hf2*)(ws + M);                   // 0.5M floats
    hf2*   kvh    = (hf2*)(ws + M + M / 2);           // 1M floats
    float* Apart  = ws + (M * 9) / 2;                 // nch*M
    float* lpart  = Apart + (size_t)nch * M;          // nch*BHS_TOT
    float* pp     = lpart + (size_t)nch * BHS_TOT;    // [16][8][64]

    k_embed<<<BB * SS, 64, 0, stream>>>(x, Wemb, bemb, h);
    for (int l = 0; l < NLAYER; ++l) {
        k_qkv<<<BB * SS / 4, 64, 0, stream>>>(h, Wq, bq, Wk, bk, Wv, bv, qh, kvh, l);
        k_attn<<<dim3(BB * HH, 2 * nch), 256, 0, stream>>>(qh, (const float4*)kvh, Apart, lpart, nch);
        k_projln<<<BB * SS / 4, 64, 0, stream>>>(Apart, lpart, Wo, bo, ln1g, ln1b, h, l, nch);
        k_ffn<<<BB * SS / 4, 128, 0, stream>>>(Wf1, bf1, Wf2, bf2, ln2g, ln2b, h, l);
    }
    k_pool<<<dim3(BB, 8), 64, 0, stream>>>(h, pp);
    k_tail<<<BB, 64, 0, stream>>>(pp, Wp1, bp1, Wp2, bp2, qwts, out);
}

// Round 17
// 359.022 us; speedup vs baseline: 1.0327x; 1.0327x over previous
//
#include <hip/hip_runtime.h>
#include <math.h>

#define BB 16
#define SS 1024
#define NF 5
#define DD 64
#define HH 8
#define HDIM 8
#define NLAYER 2
#define FFD 128
#define NQ 8
#define QLAY 3
#define NC 3
#define NSWEEP 5
#define BHS_TOT (BB * HH * SS)   // 131072 = 1<<17

typedef __fp16 hf2 __attribute__((ext_vector_type(2)));
__device__ inline hf2 ash2(float f) { union { float f; hf2 h; } u; u.f = f; return u.h; }

// ---------------- embed + positional encoding ----------------
__global__ __launch_bounds__(64) void k_embed(const float* __restrict__ x,
                                              const float* __restrict__ Wemb,
                                              const float* __restrict__ bemb,
                                              float* __restrict__ h) {
    int bs = blockIdx.x;            // 0..B*S-1
    int s  = bs & (SS - 1);
    int d  = threadIdx.x;           // 0..63
    const float* xr = x + bs * NF;
    float acc = bemb[d];
#pragma unroll
    for (int f = 0; f < NF; ++f) acc += xr[f] * Wemb[f * DD + d];
    int i = d >> 1;
    float div = expf((float)(2 * i) * (-9.210340371976184f / 64.0f));
    float ang = (float)s * div;
    float pe = (d & 1) ? cosf(ang) : sinf(ang);
    h[bs * DD + d] = acc + pe;
}

// ---------------- fused q,k,v projection (4 rows/block; f16 packed out) -----
__global__ __launch_bounds__(64) void k_qkv(const float* __restrict__ h,
                                            const float* __restrict__ Wq, const float* __restrict__ bq,
                                            const float* __restrict__ Wk, const float* __restrict__ bk,
                                            const float* __restrict__ Wv, const float* __restrict__ bv,
                                            hf2* __restrict__ qh, hf2* __restrict__ kvh, int l) {
    __shared__ float hrow[4][DD];
    int d   = threadIdx.x;
    int bs0 = blockIdx.x * 4;
#pragma unroll
    for (int r = 0; r < 4; ++r) hrow[r][d] = h[(bs0 + r) * DD + d];
    __syncthreads();
    const float* wq = Wq + l * DD * DD;
    const float* wk = Wk + l * DD * DD;
    const float* wv = Wv + l * DD * DD;
    float aq[4], ak[4], av[4];
    float bqv = bq[l * DD + d], bkv = bk[l * DD + d], bvv = bv[l * DD + d];
#pragma unroll
    for (int r = 0; r < 4; ++r) { aq[r] = bqv; ak[r] = bkv; av[r] = bvv; }
#pragma unroll 4
    for (int i = 0; i < DD; ++i) {
        float wqv = wq[i * DD + d], wkv = wk[i * DD + d], wvv = wv[i * DD + d];
#pragma unroll
        for (int r = 0; r < 4; ++r) {
            float hv = hrow[r][i];
            aq[r] += hv * wqv; ak[r] += hv * wkv; av[r] += hv * wvv;
        }
    }
    int hh = d >> 3, hd = d & 7;
    const float qs = 0.3535533906f;
    float aqp[4], akp[4];
#pragma unroll
    for (int r = 0; r < 4; ++r) { aqp[r] = __shfl_xor(aq[r], 1); akp[r] = __shfl_xor(ak[r], 1); }
    if ((hd & 1) == 0) {
#pragma unroll
        for (int r = 0; r < 4; ++r) {
            int bs = bs0 + r;
            int b = bs >> 10, s = bs & 1023;
            int bh = b * HH + hh;
            int bhs = (bh << 10) | s;
            qh[bhs * 4 + (hd >> 1)] = __builtin_amdgcn_cvt_pkrtz(aq[r] * qs, aqp[r] * qs);
            int tp = s >> 1, par = s & 1;
            kvh[(bh * 512 + tp) * 16 + par * 4 + (hd >> 1)] =
                __builtin_amdgcn_cvt_pkrtz(ak[r], akp[r]);
        }
    }
#pragma unroll
    for (int r = 0; r < 4; r += 2) {
        int bs = bs0 + r;
        int b = bs >> 10, s = bs & 1023;
        int bh = b * HH + hh;
        int tp = s >> 1;
        kvh[(bh * 512 + tp) * 16 + 8 + hd] = __builtin_amdgcn_cvt_pkrtz(av[r], av[r + 1]);
    }
}

// ---------------- attention: f16 dot2, kv chunk staged in LDS (r15 best) ----
__global__ __launch_bounds__(256) void k_attn(const hf2* __restrict__ qh,
                                              const float4* __restrict__ kvh4,
                                              float* __restrict__ Apart,   // [nch][BHS][8]
                                              float* __restrict__ lpart,   // [nch][BHS]
                                              int nch) {
    __shared__ float4 KVs[1024];      // up to 16 KB (tpc<=256)
    int bh  = blockIdx.x;             // 0..127
    int sg  = blockIdx.y & 3;
    int ch  = blockIdx.y >> 2;
    int tid = threadIdx.x;
    int s   = sg * 256 + tid;
    int tpc = 512 / nch;              // t-pairs per chunk
    const float4* kp = kvh4 + (size_t)(bh * 512 + ch * tpc) * 4;
    for (int i = tid; i < tpc * 4; i += 256) KVs[i] = kp[i];
    float4 qv = ((const float4*)qh)[(bh << 10) | s];
    hf2 q01 = ash2(qv.x), q23 = ash2(qv.y), q45 = ash2(qv.z), q67 = ash2(qv.w);
    hf2 one2 = __builtin_amdgcn_cvt_pkrtz(1.f, 1.f);
    float ls = 0.f;
    float A[8] = {0,0,0,0,0,0,0,0};
    __syncthreads();
#pragma unroll 2
    for (int t = 0; t < tpc; ++t) {
        float4 f0 = KVs[4*t], f1 = KVs[4*t+1], f2 = KVs[4*t+2], f3 = KVs[4*t+3];
        float sc0 = __builtin_amdgcn_fdot2(q67, ash2(f0.w),
                    __builtin_amdgcn_fdot2(q45, ash2(f0.z),
                    __builtin_amdgcn_fdot2(q23, ash2(f0.y),
                    __builtin_amdgcn_fdot2(q01, ash2(f0.x), 0.f, false), false), false), false);
        float sc1 = __builtin_amdgcn_fdot2(q67, ash2(f1.w),
                    __builtin_amdgcn_fdot2(q45, ash2(f1.z),
                    __builtin_amdgcn_fdot2(q23, ash2(f1.y),
                    __builtin_amdgcn_fdot2(q01, ash2(f1.x), 0.f, false), false), false), false);
        float p0 = __expf(sc0), p1 = __expf(sc1);
        hf2 pp = __builtin_amdgcn_cvt_pkrtz(p0, p1);
        ls   = __builtin_amdgcn_fdot2(pp, one2,       ls,   false);
        A[0] = __builtin_amdgcn_fdot2(pp, ash2(f2.x), A[0], false);
        A[1] = __builtin_amdgcn_fdot2(pp, ash2(f2.y), A[1], false);
        A[2] = __builtin_amdgcn_fdot2(pp, ash2(f2.z), A[2], false);
        A[3] = __builtin_amdgcn_fdot2(pp, ash2(f2.w), A[3], false);
        A[4] = __builtin_amdgcn_fdot2(pp, ash2(f3.x), A[4], false);
        A[5] = __builtin_amdgcn_fdot2(pp, ash2(f3.y), A[5], false);
        A[6] = __builtin_amdgcn_fdot2(pp, ash2(f3.z), A[6], false);
        A[7] = __builtin_amdgcn_fdot2(pp, ash2(f3.w), A[7], false);
    }
    int bhs = (bh << 10) | s;
    float* arow = Apart + (((size_t)ch << 17) + bhs) * 8;
    ((float4*)arow)[0] = make_float4(A[0], A[1], A[2], A[3]);
    ((float4*)arow)[1] = make_float4(A[4], A[5], A[6], A[7]);
    lpart[((size_t)ch << 17) + bhs] = ls;
}

// ---------------- fused mid: combine + Oproj + LN1 + FFN1 + FFN2 + LN2 ------
// 128 threads, 4 rows/block. LN1 output (h1) stays in LDS — never hits global.
__global__ __launch_bounds__(128) void k_mid(const float* __restrict__ Apart,
                                             const float* __restrict__ lpart,
                                             const float* __restrict__ Wo, const float* __restrict__ bo,
                                             const float* __restrict__ g1, const float* __restrict__ b1,
                                             const float* __restrict__ Wf1, const float* __restrict__ bf1,
                                             const float* __restrict__ Wf2, const float* __restrict__ bf2,
                                             const float* __restrict__ g2, const float* __restrict__ b2,
                                             float* __restrict__ h, int l, int nch) {
    __shared__ float orow[4][DD];
    __shared__ float h1s[4][DD];
    __shared__ float frow[4][FFD];
    int t    = threadIdx.x;
    int d    = t & 63;
    int half = t >> 6;
    int bs0  = blockIdx.x * 4;
    int hh = d >> 3, hd = d & 7;
    int r0 = half * 2, r1 = r0 + 1;

    // ---- combine attention partials (each wave: 2 rows) ----
#pragma unroll
    for (int rr = 0; rr < 2; ++rr) {
        int r  = r0 + rr;
        int bs = bs0 + r;
        int b = bs >> 10, s = bs & 1023;
        int bhs = ((b * HH + hh) << 10) | s;
        float a = 0.f, lt = 0.f;
        for (int ch = 0; ch < nch; ++ch) {
            a  += Apart[(((size_t)ch << 17) + bhs) * 8 + hd];
            lt += lpart[((size_t)ch << 17) + bhs];
        }
        orow[r][d] = a / lt;
    }
    __syncthreads();

    // ---- Oproj + residual + LN1 -> h1s (LDS only) ----
    {
        const float* w = Wo + l * DD * DD;
        float bias = bo[l * DD + d];
        float acc0 = bias, acc1 = bias;
#pragma unroll 4
        for (int i = 0; i < DD; ++i) {
            float wv = w[i * DD + d];
            acc0 += orow[r0][i] * wv;
            acc1 += orow[r1][i] * wv;
        }
        float gg = g1[l * DD + d], bb = b1[l * DD + d];
        float accs[2] = {acc0, acc1};
#pragma unroll
        for (int rr = 0; rr < 2; ++rr) {
            int r = r0 + rr;
            float a = accs[rr] + h[(bs0 + r) * DD + d];
            float sum = a;
            for (int off = 32; off; off >>= 1) sum += __shfl_xor(sum, off);
            float mean = sum * (1.f / 64.f);
            float dx = a - mean;
            float vs = dx * dx;
            for (int off = 32; off; off >>= 1) vs += __shfl_xor(vs, off);
            float rstd = rsqrtf(vs * (1.f / 64.f) + 1e-5f);
            h1s[r][d] = dx * rstd * gg + bb;
        }
    }
    __syncthreads();

    // ---- FFN1 (relu): thread t = f index ----
    {
        const float* w = Wf1 + l * DD * FFD;
        float bv = bf1[l * FFD + t];
        float a0 = bv, a1 = bv, a2 = bv, a3 = bv;
#pragma unroll 4
        for (int i = 0; i < DD; ++i) {
            float wv = w[i * FFD + t];
            a0 += h1s[0][i]*wv; a1 += h1s[1][i]*wv;
            a2 += h1s[2][i]*wv; a3 += h1s[3][i]*wv;
        }
        frow[0][t] = fmaxf(a0, 0.f); frow[1][t] = fmaxf(a1, 0.f);
        frow[2][t] = fmaxf(a2, 0.f); frow[3][t] = fmaxf(a3, 0.f);
    }
    __syncthreads();

    // ---- FFN2 + residual(h1s) + LN2 -> h ----
    {
        const float* w = Wf2 + l * FFD * DD;
        float bias = bf2[l * DD + d];
        float acc0 = bias, acc1 = bias;
#pragma unroll 4
        for (int i = 0; i < FFD; ++i) {
            float wv = w[i * DD + d];
            acc0 += frow[r0][i] * wv;
            acc1 += frow[r1][i] * wv;
        }
        float gg = g2[l * DD + d], bb = b2[l * DD + d];
        float accs[2] = {acc0, acc1};
#pragma unroll
        for (int rr = 0; rr < 2; ++rr) {
            int r = r0 + rr;
            float a = accs[rr] + h1s[r][d];
            float sum = a;
            for (int off = 32; off; off >>= 1) sum += __shfl_xor(sum, off);
            float mean = sum * (1.f / 64.f);
            float dx = a - mean;
            float vs = dx * dx;
            for (int off = 32; off; off >>= 1) vs += __shfl_xor(vs, off);
            float rstd = rsqrtf(vs * (1.f / 64.f) + 1e-5f);
            h[(bs0 + r) * DD + d] = dx * rstd * gg + bb;
        }
    }
}

// ---------------- mean pool over sequence (8-way split) ----------------
__global__ __launch_bounds__(64) void k_pool(const float* __restrict__ h, float* __restrict__ pp) {
    int b = blockIdx.x, c = blockIdx.y, d = threadIdx.x;
    const float* hp = h + (b * SS + c * 128) * DD + d;
    float acc = 0.f;
#pragma unroll 8
    for (int s = 0; s < 128; ++s) acc += hp[s * DD];
    pp[(b * 8 + c) * DD + d] = acc;
}

// ---------------- fused tail: head (angles) + quantum circuit + eigensolver -
__global__ __launch_bounds__(64) void k_tail(const float* __restrict__ pp,
                                             const float* __restrict__ Wp1, const float* __restrict__ bp1,
                                             const float* __restrict__ Wp2, const float* __restrict__ bp2,
                                             const float* __restrict__ qw,
                                             float* __restrict__ out) {
    __shared__ float pool_s[DD];
    __shared__ float hid[32];
    __shared__ float ang_s[NQ];
    __shared__ float2 Ps2[256];
    int b = blockIdx.x; int L = threadIdx.x;

    // ---- head ----
    {
        float acc = 0.f;
#pragma unroll
        for (int c = 0; c < 8; ++c) acc += pp[(b * 8 + c) * DD + L];
        pool_s[L] = acc * (1.f / 1024.f);
    }
    __syncthreads();
    if (L < 32) {
        float a = bp1[L];
        for (int i = 0; i < DD; ++i) a += pool_s[i] * Wp1[i * 32 + L];
        hid[L] = fmaxf(a, 0.f);
    }
    __syncthreads();
    if (L < NQ) {
        float a = bp2[L];
        for (int j = 0; j < 32; ++j) a += hid[j] * Wp2[j * NQ + L];
        ang_s[L] = tanhf(a) * 3.14159265358979f;
    }
    __syncthreads();

    // ---- quantum circuit ----
    float ar[4], ai[4];
#pragma unroll
    for (int r = 0; r < 4; ++r) { ar[r] = 0.f; ai[r] = 0.f; }
    if (L == 0) ar[0] = 1.f;

    for (int l = 0; l < QLAY; ++l) {
#pragma unroll
        for (int w = 0; w < NQ; ++w) {
            int p = 7 - w;
            float half = 0.5f * ang_s[w];
            float c = cosf(half), s = sinf(half);
            if (p == 7) {
#pragma unroll
                for (int lo = 0; lo < 2; ++lo) {
                    int hi = lo + 2;
                    float r0=ar[lo], m0=ai[lo], r1=ar[hi], m1=ai[hi];
                    ar[lo] = c*r0 + s*m1;  ai[lo] = c*m0 - s*r1;
                    ar[hi] = c*r1 + s*m0;  ai[hi] = c*m1 - s*r0;
                }
            } else if (p == 6) {
#pragma unroll
                for (int base = 0; base < 4; base += 2) {
                    int lo = base, hi = base + 1;
                    float r0=ar[lo], m0=ai[lo], r1=ar[hi], m1=ai[hi];
                    ar[lo] = c*r0 + s*m1;  ai[lo] = c*m0 - s*r1;
                    ar[hi] = c*r1 + s*m0;  ai[hi] = c*m1 - s*r0;
                }
            } else {
                int mask = 1 << p;
#pragma unroll
                for (int r = 0; r < 4; ++r) {
                    float pre = __shfl_xor(ar[r], mask);
                    float pim = __shfl_xor(ai[r], mask);
                    float nr = c*ar[r] + s*pim;
                    float ni = c*ai[r] - s*pre;
                    ar[r] = nr; ai[r] = ni;
                }
            }
        }
#pragma unroll
        for (int w = 0; w < NQ; ++w) {
            const float* p3 = qw + (l * NQ + w) * 3;
            float phi = p3[0], th = p3[1], om = p3[2];
            float ct = cosf(0.5f * th), st = sinf(0.5f * th);
            float al = 0.5f * (phi + om), be = 0.5f * (phi - om);
            float ca = cosf(al), sa = sinf(al), cb = cosf(be), sb = sinf(be);
            float u00r =  ct * ca, u00i = -ct * sa;
            float u01r = -st * cb, u01i = -st * sb;
            float u10r =  st * cb, u10i = -st * sb;
            float u11r =  ct * ca, u11i =  ct * sa;
            int p = 7 - w;
            if (p >= 6) {
#pragma unroll
                for (int pi_ = 0; pi_ < 2; ++pi_) {
                    int lo = (p == 7) ? pi_ : pi_ * 2;
                    int hi = (p == 7) ? pi_ + 2 : pi_ * 2 + 1;
                    float r0=ar[lo], m0=ai[lo], r1=ar[hi], m1=ai[hi];
                    ar[lo] = u00r*r0 - u00i*m0 + u01r*r1 - u01i*m1;
                    ai[lo] = u00r*m0 + u00i*r0 + u01r*m1 + u01i*r1;
                    ar[hi] = u10r*r0 - u10i*m0 + u11r*r1 - u11i*m1;
                    ai[hi] = u10r*m0 + u10i*r0 + u11r*m1 + u11i*r1;
                }
            } else {
                int mask = 1 << p;
                int bit = (L >> p) & 1;
                float car = bit ? u11r : u00r, cai = bit ? u11i : u00i;
                float cpr = bit ? u10r : u01r, cpi = bit ? u10i : u01i;
#pragma unroll
                for (int r = 0; r < 4; ++r) {
                    float pre = __shfl_xor(ar[r], mask);
                    float pim = __shfl_xor(ai[r], mask);
                    float nr = car*ar[r] - cai*ai[r] + cpr*pre - cpi*pim;
                    float ni = car*ai[r] + cai*ar[r] + cpr*pim + cpi*pre;
                    ar[r] = nr; ai[r] = ni;
                }
            }
        }
        { float t0=ar[2]; ar[2]=ar[3]; ar[3]=t0; t0=ai[2]; ai[2]=ai[3]; ai[3]=t0; }
        ar[1]=__shfl_xor(ar[1],32); ai[1]=__shfl_xor(ai[1],32);
        ar[3]=__shfl_xor(ar[3],32); ai[3]=__shfl_xor(ai[3],32);
#pragma unroll
        for (int w = 2; w <= 6; ++w) {
            int pc = 7 - w, pt = 6 - w;
            int tm = 1 << pt;
            bool ctrl = (L >> pc) & 1;
#pragma unroll
            for (int r = 0; r < 4; ++r) {
                float swr = __shfl_xor(ar[r], tm);
                float swi = __shfl_xor(ai[r], tm);
                ar[r] = ctrl ? swr : ar[r];
                ai[r] = ctrl ? swi : ai[r];
            }
        }
        {
            bool ctrl = L & 1;
            float n0r = ctrl ? ar[2] : ar[0], n2r = ctrl ? ar[0] : ar[2];
            float n0i = ctrl ? ai[2] : ai[0], n2i = ctrl ? ai[0] : ai[2];
            float n1r = ctrl ? ar[3] : ar[1], n3r = ctrl ? ar[1] : ar[3];
            float n1i = ctrl ? ai[3] : ai[1], n3i = ctrl ? ai[1] : ai[3];
            ar[0]=n0r; ar[1]=n1r; ar[2]=n2r; ar[3]=n3r;
            ai[0]=n0i; ai[1]=n1i; ai[2]=n2i; ai[3]=n3i;
        }
    }

    // ---- <Z_w>, w=0..2 ----
    {
        float p0 = ar[0]*ar[0]+ai[0]*ai[0];
        float p1 = ar[1]*ar[1]+ai[1]*ai[1];
        float p2 = ar[2]*ar[2]+ai[2]*ai[2];
        float p3 = ar[3]*ar[3]+ai[3]*ai[3];
        float z0 = p0 + p1 - p2 - p3;
        float z1 = p0 - p1 + p2 - p3;
        float zs = p0 + p1 + p2 + p3;
        float z2 = (L & 32) ? -zs : zs;
#pragma unroll
        for (int off = 1; off < 64; off <<= 1) {
            z0 += __shfl_xor(z0, off);
            z1 += __shfl_xor(z1, off);
            z2 += __shfl_xor(z2, off);
        }
        if (L == 0) {
            out[b * NC + 0] = z0;
            out[b * NC + 1] = z1;
            out[b * NC + 2] = z2;
        }
    }

    // ---- hand off psi through LDS, redistribute to column layout ----
#pragma unroll
    for (int r = 0; r < 4; ++r) Ps2[(r << 6) | L] = make_float2(ar[r], ai[r]);
    __syncthreads();
    int c   = L >> 2;                 // my column
    int seg = L & 3;                  // my segment (4 elements)
    float gr[4], gi[4];
#pragma unroll
    for (int j = 0; j < 4; ++j) {
        float2 t = Ps2[(seg * 4 + j) * 16 + c];
        gr[j] = t.x; gi[j] = t.y;
    }
    float alm = 0.f;
#pragma unroll
    for (int j = 0; j < 4; ++j) alm += gr[j]*gr[j] + gi[j]*gi[j];
    alm += __shfl_xor(alm, 1);
    alm += __shfl_xor(alm, 2);

    // ---- one-sided Jacobi: XOR tournament, shfl_xor exchange ----
    for (int sweep = 0; sweep < NSWEEP; ++sweep) {
#pragma unroll 1
        for (int m = 1; m <= 15; ++m) {
            int xm = m << 2;          // lane xor mask (column bits)
            float pgr[4], pgi[4];
#pragma unroll
            for (int j = 0; j < 4; ++j) {
                pgr[j] = __shfl_xor(gr[j], xm);
                pgi[j] = __shfl_xor(gi[j], xm);
            }
            float bep = __shfl_xor(alm, xm);   // partner norm (same latency group)
            float d = 0.f, e = 0.f;
#pragma unroll
            for (int j = 0; j < 4; ++j) {
                d += gr[j]*pgr[j] + gi[j]*pgi[j];   // Re(mine^H partner)
                e += gr[j]*pgi[j] - gi[j]*pgr[j];   // Im(mine^H partner)
            }
            d += __shfl_xor(d, 1); e += __shfl_xor(e, 1);
            d += __shfl_xor(d, 2); e += __shfl_xor(e, 2);
            float g2 = d*d + e*e;
            float cth = 1.f, sth = 0.f, cph = 1.f, sph = 0.f, gn = 0.f;
            if (g2 > 1e-26f) {
                gn = sqrtf(g2);
                float ginv = 1.f / gn;
                cph = d * ginv; sph = -e * ginv;    // conj(gamma)/|gamma|
                float tau = (alm - bep) * (0.5f * ginv);
                float t = ((tau >= 0.f) ? 1.f : -1.f) / (fabsf(tau) + sqrtf(1.f + tau*tau));
                cth = rsqrtf(1.f + t*t);
                sth = t * cth;
            }
#pragma unroll
            for (int j = 0; j < 4; ++j) {
                float er = cph*pgr[j] - sph*pgi[j];
                float ei = cph*pgi[j] + sph*pgr[j];
                gr[j] = cth * gr[j] + sth * er;
                gi[j] = cth * gi[j] + sth * ei;
            }
            alm = cth*cth*alm + sth*sth*bep + 2.f*cth*sth*gn;
        }
    }

    float ev = fminf(fmaxf(alm, 1e-10f), 1.0f);
    float term = -ev * logf(ev);
#pragma unroll
    for (int off = 4; off < 64; off <<= 1) term += __shfl_xor(term, off);
    if (L == 0) out[BB * NC + b] = term;
}

extern "C" void kernel_launch(void* const* d_in, const int* in_sizes, int n_in,
                              void* d_out, int out_size, void* d_ws, size_t ws_size,
                              hipStream_t stream) {
    const float* x    = (const float*)d_in[0];
    const float* Wemb = (const float*)d_in[1];
    const float* bemb = (const float*)d_in[2];
    const float* Wq   = (const float*)d_in[3];
    const float* bq   = (const float*)d_in[4];
    const float* Wk   = (const float*)d_in[5];
    const float* bk   = (const float*)d_in[6];
    const float* Wv   = (const float*)d_in[7];
    const float* bv   = (const float*)d_in[8];
    const float* Wo   = (const float*)d_in[9];
    const float* bo   = (const float*)d_in[10];
    const float* ln1g = (const float*)d_in[11];
    const float* ln1b = (const float*)d_in[12];
    const float* ln2g = (const float*)d_in[13];
    const float* ln2b = (const float*)d_in[14];
    const float* Wf1  = (const float*)d_in[15];
    const float* bf1  = (const float*)d_in[16];
    const float* Wf2  = (const float*)d_in[17];
    const float* bf2  = (const float*)d_in[18];
    const float* Wp1  = (const float*)d_in[19];
    const float* bp1  = (const float*)d_in[20];
    const float* Wp2  = (const float*)d_in[21];
    const float* bp2  = (const float*)d_in[22];
    const float* qwts = (const float*)d_in[23];
    float* out = (float*)d_out;

    const size_t M = 1u << 20;           // 1M floats = B*S*D
    auto needF = [&](int nch) {
        return (size_t)(4.5 * M) + (size_t)nch * M + (size_t)nch * BHS_TOT + BB * 8 * DD + 16384;
    };
    int nch = (ws_size >= needF(4) * sizeof(float)) ? 4 : 2;

    float* ws     = (float*)d_ws;
    float* h      = ws;                               // 1M
    hf2*   qh     = (hf2*)(ws + M);                   // 0.5M floats
    hf2*   kvh    = (hf2*)(ws + M + M / 2);           // 1M floats
    float* Apart  = ws + (M * 9) / 2;                 // nch*M
    float* lpart  = Apart + (size_t)nch * M;          // nch*BHS_TOT
    float* pp     = lpart + (size_t)nch * BHS_TOT;    // [16][8][64]

    k_embed<<<BB * SS, 64, 0, stream>>>(x, Wemb, bemb, h);
    for (int l = 0; l < NLAYER; ++l) {
        k_qkv<<<BB * SS / 4, 64, 0, stream>>>(h, Wq, bq, Wk, bk, Wv, bv, qh, kvh, l);
        k_attn<<<dim3(BB * HH, 4 * nch), 256, 0, stream>>>(qh, (const float4*)kvh, Apart, lpart, nch);
        k_mid<<<BB * SS / 4, 128, 0, stream>>>(Apart, lpart, Wo, bo, ln1g, ln1b,
                                               Wf1, bf1, Wf2, bf2, ln2g, ln2b, h, l, nch);
    }
    k_pool<<<dim3(BB, 8), 64, 0, stream>>>(h, pp);
    k_tail<<<BB, 64, 0, stream>>>(pp, Wp1, bp1, Wp2, bp2, qwts, out);
}

// Round 18
// 318.975 us; speedup vs baseline: 1.1624x; 1.1255x over previous
//
#include <hip/hip_runtime.h>
#include <math.h>

#define BB 16
#define SS 1024
#define NF 5
#define DD 64
#define HH 8
#define HDIM 8
#define NLAYER 2
#define FFD 128
#define NQ 8
#define QLAY 3
#define NC 3
#define NSWEEP 5
#define BHS_TOT (BB * HH * SS)   // 131072 = 1<<17

typedef __fp16 hf2 __attribute__((ext_vector_type(2)));
typedef __fp16 h8  __attribute__((ext_vector_type(8)));
typedef float  f4x __attribute__((ext_vector_type(4)));
__device__ inline hf2 ash2(float f) { union { float f; hf2 h; } u; u.f = f; return u.h; }

// ---------------- embed + positional encoding ----------------
__global__ __launch_bounds__(64) void k_embed(const float* __restrict__ x,
                                              const float* __restrict__ Wemb,
                                              const float* __restrict__ bemb,
                                              float* __restrict__ h) {
    int bs = blockIdx.x;            // 0..B*S-1
    int s  = bs & (SS - 1);
    int d  = threadIdx.x;           // 0..63
    const float* xr = x + bs * NF;
    float acc = bemb[d];
#pragma unroll
    for (int f = 0; f < NF; ++f) acc += xr[f] * Wemb[f * DD + d];
    int i = d >> 1;
    float div = expf((float)(2 * i) * (-9.210340371976184f / 64.0f));
    float ang = (float)s * div;
    float pe = (d & 1) ? cosf(ang) : sinf(ang);
    h[bs * DD + d] = acc + pe;
}

// ---------------- fused q,k,v projection (4 rows/block) ---------------------
// Outputs: qh [BHS][8] f16 (pre-scaled), kh [BHS][8] f16, vt [BH*8][S] f16.
__global__ __launch_bounds__(64) void k_qkv(const float* __restrict__ h,
                                            const float* __restrict__ Wq, const float* __restrict__ bq,
                                            const float* __restrict__ Wk, const float* __restrict__ bk,
                                            const float* __restrict__ Wv, const float* __restrict__ bv,
                                            hf2* __restrict__ qh, hf2* __restrict__ kh,
                                            hf2* __restrict__ vt, int l) {
    __shared__ float hrow[4][DD];
    int d   = threadIdx.x;
    int bs0 = blockIdx.x * 4;
#pragma unroll
    for (int r = 0; r < 4; ++r) hrow[r][d] = h[(bs0 + r) * DD + d];
    __syncthreads();
    const float* wq = Wq + l * DD * DD;
    const float* wk = Wk + l * DD * DD;
    const float* wv = Wv + l * DD * DD;
    float aq[4], ak[4], av[4];
    float bqv = bq[l * DD + d], bkv = bk[l * DD + d], bvv = bv[l * DD + d];
#pragma unroll
    for (int r = 0; r < 4; ++r) { aq[r] = bqv; ak[r] = bkv; av[r] = bvv; }
#pragma unroll 4
    for (int i = 0; i < DD; ++i) {
        float wqv = wq[i * DD + d], wkv = wk[i * DD + d], wvv = wv[i * DD + d];
#pragma unroll
        for (int r = 0; r < 4; ++r) {
            float hv = hrow[r][i];
            aq[r] += hv * wqv; ak[r] += hv * wkv; av[r] += hv * wvv;
        }
    }
    int hh = d >> 3, hd = d & 7;
    const float qs = 0.3535533906f;
    float aqp[4], akp[4];
#pragma unroll
    for (int r = 0; r < 4; ++r) { aqp[r] = __shfl_xor(aq[r], 1); akp[r] = __shfl_xor(ak[r], 1); }
    if ((hd & 1) == 0) {
#pragma unroll
        for (int r = 0; r < 4; ++r) {
            int bs = bs0 + r;
            int b = bs >> 10, s = bs & 1023;
            int bhs = ((b * HH + hh) << 10) | s;
            qh[bhs * 4 + (hd >> 1)] = __builtin_amdgcn_cvt_pkrtz(aq[r] * qs, aqp[r] * qs);
            kh[bhs * 4 + (hd >> 1)] = __builtin_amdgcn_cvt_pkrtz(ak[r], akp[r]);
        }
    }
    // V transposed: vt[(bh*8+hd)][s] halves; rows bs0..bs0+3 are consecutive s.
    {
        int b = bs0 >> 10, s0 = bs0 & 1023;
        int vrow = (b * HH + hh) * 8 + hd;
        hf2* vp = vt + vrow * 512 + (s0 >> 1);
        vp[0] = __builtin_amdgcn_cvt_pkrtz(av[0], av[1]);
        vp[1] = __builtin_amdgcn_cvt_pkrtz(av[2], av[3]);
    }
}

// ---------------- attention via MFMA (flash-style, full-t per wave) ---------
// Block = (bh, 64-row Q slab); 4 waves x 16 Q rows. QK^T: mfma 16x16x32 f16
// with K-dim=8 zero-padded. P re-layout C->A via per-wave LDS (stride 36).
// PV: 32 mfmas against transposed V. Writes normalized O to Ao [BHS][8] f32.
__global__ __launch_bounds__(256) void k_attn(const float4* __restrict__ qh4,
                                              const float4* __restrict__ kh4,
                                              const float4* __restrict__ vt4,
                                              float* __restrict__ Ao) {
    __shared__ float Pbuf[4][16 * 36];
    int bh  = blockIdx.x;             // 0..127
    int sb  = blockIdx.y;             // 0..15
    int tid = threadIdx.x;
    int wv  = tid >> 6;
    int L   = tid & 63;
    int m = L & 15, quad = L >> 4;
    union U { float4 f; h8 h; };
    h8 hz = {0,0,0,0,0,0,0,0};
    h8 aQ = hz;
    if (quad == 0) { U u; u.f = qh4[(bh << 10) | (sb * 64 + wv * 16 + m)]; aQ = u.h; }
    float* Pw = Pbuf[wv];
    f4x Oacc = {0.f, 0.f, 0.f, 0.f};
    float ls0 = 0.f, ls1 = 0.f, ls2 = 0.f, ls3 = 0.f;
    int rb = quad * 4;
    for (int kc = 0; kc < 32; ++kc) {
        h8 bk0 = hz, bk1 = hz;
        if (quad == 0) {
            U u0, u1;
            u0.f = kh4[(bh << 10) | (kc * 32 + m)];
            u1.f = kh4[(bh << 10) | (kc * 32 + 16 + m)];
            bk0 = u0.h; bk1 = u1.h;
        }
        f4x S0 = {0.f,0.f,0.f,0.f}, S1 = {0.f,0.f,0.f,0.f};
        S0 = __builtin_amdgcn_mfma_f32_16x16x32_f16(aQ, bk0, S0, 0, 0, 0);
        S1 = __builtin_amdgcn_mfma_f32_16x16x32_f16(aQ, bk1, S1, 0, 0, 0);
        float p00 = __expf(S0[0]), p01 = __expf(S0[1]);
        float p02 = __expf(S0[2]), p03 = __expf(S0[3]);
        float p10 = __expf(S1[0]), p11 = __expf(S1[1]);
        float p12 = __expf(S1[2]), p13 = __expf(S1[3]);
        ls0 += p00 + p10; ls1 += p01 + p11; ls2 += p02 + p12; ls3 += p03 + p13;
        Pw[(rb+0)*36 + m]      = p00; Pw[(rb+1)*36 + m]      = p01;
        Pw[(rb+2)*36 + m]      = p02; Pw[(rb+3)*36 + m]      = p03;
        Pw[(rb+0)*36 + 16 + m] = p10; Pw[(rb+1)*36 + 16 + m] = p11;
        Pw[(rb+2)*36 + 16 + m] = p12; Pw[(rb+3)*36 + 16 + m] = p13;
        // read back in A-layout: A[m][k=quad*8+j], k local to this 32-chunk
        float4 pa = *(const float4*)&Pw[m * 36 + quad * 8];
        float4 pb = *(const float4*)&Pw[m * 36 + quad * 8 + 4];
        hf2 c0 = __builtin_amdgcn_cvt_pkrtz(pa.x, pa.y);
        hf2 c1 = __builtin_amdgcn_cvt_pkrtz(pa.z, pa.w);
        hf2 c2 = __builtin_amdgcn_cvt_pkrtz(pb.x, pb.y);
        hf2 c3 = __builtin_amdgcn_cvt_pkrtz(pb.z, pb.w);
        h8 aP;
        aP[0] = c0[0]; aP[1] = c0[1]; aP[2] = c1[0]; aP[3] = c1[1];
        aP[4] = c2[0]; aP[5] = c2[1]; aP[6] = c3[0]; aP[7] = c3[1];
        h8 bV = hz;
        if (m < 8) {
            U uv; uv.f = vt4[((bh * 8 + m) << 7) | (kc * 4 + quad)];
            bV = uv.h;
        }
        Oacc = __builtin_amdgcn_mfma_f32_16x16x32_f16(aP, bV, Oacc, 0, 0, 0);
    }
    // reduce row sums across the 16 columns (lane bits 0..3)
#pragma unroll
    for (int off = 1; off <= 8; off <<= 1) {
        ls0 += __shfl_xor(ls0, off); ls1 += __shfl_xor(ls1, off);
        ls2 += __shfl_xor(ls2, off); ls3 += __shfl_xor(ls3, off);
    }
    if (m < 8) {
        int srow = sb * 64 + wv * 16 + rb;
        int base = (((bh << 10) | srow) << 3) + m;
        Ao[base]      = Oacc[0] / ls0;
        Ao[base + 8]  = Oacc[1] / ls1;
        Ao[base + 16] = Oacc[2] / ls2;
        Ao[base + 24] = Oacc[3] / ls3;
    }
}

// ---------------- fused mid: Oproj + LN1 + FFN1 + FFN2 + LN2 ----------------
// 128 threads, 4 rows/block. Reads normalized attention output Ao.
__global__ __launch_bounds__(128) void k_mid(const float* __restrict__ Ao,
                                             const float* __restrict__ Wo, const float* __restrict__ bo,
                                             const float* __restrict__ g1, const float* __restrict__ b1,
                                             const float* __restrict__ Wf1, const float* __restrict__ bf1,
                                             const float* __restrict__ Wf2, const float* __restrict__ bf2,
                                             const float* __restrict__ g2, const float* __restrict__ b2,
                                             float* __restrict__ h, int l) {
    __shared__ float orow[4][DD];
    __shared__ float h1s[4][DD];
    __shared__ float frow[4][FFD];
    int t    = threadIdx.x;
    int d    = t & 63;
    int half = t >> 6;
    int bs0  = blockIdx.x * 4;
    int hh = d >> 3, hd = d & 7;
    int r0 = half * 2, r1 = r0 + 1;

#pragma unroll
    for (int rr = 0; rr < 2; ++rr) {
        int r  = r0 + rr;
        int bs = bs0 + r;
        int b = bs >> 10, s = bs & 1023;
        int bhs = ((b * HH + hh) << 10) | s;
        orow[r][d] = Ao[(bhs << 3) + hd];
    }
    __syncthreads();

    {
        const float* w = Wo + l * DD * DD;
        float bias = bo[l * DD + d];
        float acc0 = bias, acc1 = bias;
#pragma unroll 4
        for (int i = 0; i < DD; ++i) {
            float wv = w[i * DD + d];
            acc0 += orow[r0][i] * wv;
            acc1 += orow[r1][i] * wv;
        }
        float gg = g1[l * DD + d], bb = b1[l * DD + d];
        float accs[2] = {acc0, acc1};
#pragma unroll
        for (int rr = 0; rr < 2; ++rr) {
            int r = r0 + rr;
            float a = accs[rr] + h[(bs0 + r) * DD + d];
            float sum = a;
            for (int off = 32; off; off >>= 1) sum += __shfl_xor(sum, off);
            float mean = sum * (1.f / 64.f);
            float dx = a - mean;
            float vs = dx * dx;
            for (int off = 32; off; off >>= 1) vs += __shfl_xor(vs, off);
            float rstd = rsqrtf(vs * (1.f / 64.f) + 1e-5f);
            h1s[r][d] = dx * rstd * gg + bb;
        }
    }
    __syncthreads();

    {
        const float* w = Wf1 + l * DD * FFD;
        float bv = bf1[l * FFD + t];
        float a0 = bv, a1 = bv, a2 = bv, a3 = bv;
#pragma unroll 4
        for (int i = 0; i < DD; ++i) {
            float wv = w[i * FFD + t];
            a0 += h1s[0][i]*wv; a1 += h1s[1][i]*wv;
            a2 += h1s[2][i]*wv; a3 += h1s[3][i]*wv;
        }
        frow[0][t] = fmaxf(a0, 0.f); frow[1][t] = fmaxf(a1, 0.f);
        frow[2][t] = fmaxf(a2, 0.f); frow[3][t] = fmaxf(a3, 0.f);
    }
    __syncthreads();

    {
        const float* w = Wf2 + l * FFD * DD;
        float bias = bf2[l * DD + d];
        float acc0 = bias, acc1 = bias;
#pragma unroll 4
        for (int i = 0; i < FFD; ++i) {
            float wv = w[i * DD + d];
            acc0 += frow[r0][i] * wv;
            acc1 += frow[r1][i] * wv;
        }
        float gg = g2[l * DD + d], bb = b2[l * DD + d];
        float accs[2] = {acc0, acc1};
#pragma unroll
        for (int rr = 0; rr < 2; ++rr) {
            int r = r0 + rr;
            float a = accs[rr] + h1s[r][d];
            float sum = a;
            for (int off = 32; off; off >>= 1) sum += __shfl_xor(sum, off);
            float mean = sum * (1.f / 64.f);
            float dx = a - mean;
            float vs = dx * dx;
            for (int off = 32; off; off >>= 1) vs += __shfl_xor(vs, off);
            float rstd = rsqrtf(vs * (1.f / 64.f) + 1e-5f);
            h[(bs0 + r) * DD + d] = dx * rstd * gg + bb;
        }
    }
}

// ---------------- mean pool over sequence (8-way split) ----------------
__global__ __launch_bounds__(64) void k_pool(const float* __restrict__ h, float* __restrict__ pp) {
    int b = blockIdx.x, c = blockIdx.y, d = threadIdx.x;
    const float* hp = h + (b * SS + c * 128) * DD + d;
    float acc = 0.f;
#pragma unroll 8
    for (int s = 0; s < 128; ++s) acc += hp[s * DD];
    pp[(b * 8 + c) * DD + d] = acc;
}

// ---------------- fused tail: head (angles) + quantum circuit + eigensolver -
__global__ __launch_bounds__(64) void k_tail(const float* __restrict__ pp,
                                             const float* __restrict__ Wp1, const float* __restrict__ bp1,
                                             const float* __restrict__ Wp2, const float* __restrict__ bp2,
                                             const float* __restrict__ qw,
                                             float* __restrict__ out) {
    __shared__ float pool_s[DD];
    __shared__ float hid[32];
    __shared__ float ang_s[NQ];
    __shared__ float2 Ps2[256];
    int b = blockIdx.x; int L = threadIdx.x;

    // ---- head ----
    {
        float acc = 0.f;
#pragma unroll
        for (int c = 0; c < 8; ++c) acc += pp[(b * 8 + c) * DD + L];
        pool_s[L] = acc * (1.f / 1024.f);
    }
    __syncthreads();
    if (L < 32) {
        float a = bp1[L];
        for (int i = 0; i < DD; ++i) a += pool_s[i] * Wp1[i * 32 + L];
        hid[L] = fmaxf(a, 0.f);
    }
    __syncthreads();
    if (L < NQ) {
        float a = bp2[L];
        for (int j = 0; j < 32; ++j) a += hid[j] * Wp2[j * NQ + L];
        ang_s[L] = tanhf(a) * 3.14159265358979f;
    }
    __syncthreads();

    // ---- quantum circuit ----
    float ar[4], ai[4];
#pragma unroll
    for (int r = 0; r < 4; ++r) { ar[r] = 0.f; ai[r] = 0.f; }
    if (L == 0) ar[0] = 1.f;

    for (int l = 0; l < QLAY; ++l) {
#pragma unroll
        for (int w = 0; w < NQ; ++w) {
            int p = 7 - w;
            float half = 0.5f * ang_s[w];
            float c = cosf(half), s = sinf(half);
            if (p == 7) {
#pragma unroll
                for (int lo = 0; lo < 2; ++lo) {
                    int hi = lo + 2;
                    float r0=ar[lo], m0=ai[lo], r1=ar[hi], m1=ai[hi];
                    ar[lo] = c*r0 + s*m1;  ai[lo] = c*m0 - s*r1;
                    ar[hi] = c*r1 + s*m0;  ai[hi] = c*m1 - s*r0;
                }
            } else if (p == 6) {
#pragma unroll
                for (int base = 0; base < 4; base += 2) {
                    int lo = base, hi = base + 1;
                    float r0=ar[lo], m0=ai[lo], r1=ar[hi], m1=ai[hi];
                    ar[lo] = c*r0 + s*m1;  ai[lo] = c*m0 - s*r1;
                    ar[hi] = c*r1 + s*m0;  ai[hi] = c*m1 - s*r0;
                }
            } else {
                int mask = 1 << p;
#pragma unroll
                for (int r = 0; r < 4; ++r) {
                    float pre = __shfl_xor(ar[r], mask);
                    float pim = __shfl_xor(ai[r], mask);
                    float nr = c*ar[r] + s*pim;
                    float ni = c*ai[r] - s*pre;
                    ar[r] = nr; ai[r] = ni;
                }
            }
        }
#pragma unroll
        for (int w = 0; w < NQ; ++w) {
            const float* p3 = qw + (l * NQ + w) * 3;
            float phi = p3[0], th = p3[1], om = p3[2];
            float ct = cosf(0.5f * th), st = sinf(0.5f * th);
            float al = 0.5f * (phi + om), be = 0.5f * (phi - om);
            float ca = cosf(al), sa = sinf(al), cb = cosf(be), sb = sinf(be);
            float u00r =  ct * ca, u00i = -ct * sa;
            float u01r = -st * cb, u01i = -st * sb;
            float u10r =  st * cb, u10i = -st * sb;
            float u11r =  ct * ca, u11i =  ct * sa;
            int p = 7 - w;
            if (p >= 6) {
#pragma unroll
                for (int pi_ = 0; pi_ < 2; ++pi_) {
                    int lo = (p == 7) ? pi_ : pi_ * 2;
                    int hi = (p == 7) ? pi_ + 2 : pi_ * 2 + 1;
                    float r0=ar[lo], m0=ai[lo], r1=ar[hi], m1=ai[hi];
                    ar[lo] = u00r*r0 - u00i*m0 + u01r*r1 - u01i*m1;
                    ai[lo] = u00r*m0 + u00i*r0 + u01r*m1 + u01i*r1;
                    ar[hi] = u10r*r0 - u10i*m0 + u11r*r1 - u11i*m1;
                    ai[hi] = u10r*m0 + u10i*r0 + u11r*m1 + u11i*r1;
                }
            } else {
                int mask = 1 << p;
                int bit = (L >> p) & 1;
                float car = bit ? u11r : u00r, cai = bit ? u11i : u00i;
                float cpr = bit ? u10r : u01r, cpi = bit ? u10i : u01i;
#pragma unroll
                for (int r = 0; r < 4; ++r) {
                    float pre = __shfl_xor(ar[r], mask);
                    float pim = __shfl_xor(ai[r], mask);
                    float nr = car*ar[r] - cai*ai[r] + cpr*pre - cpi*pim;
                    float ni = car*ai[r] + cai*ar[r] + cpr*pim + cpi*pre;
                    ar[r] = nr; ai[r] = ni;
                }
            }
        }
        { float t0=ar[2]; ar[2]=ar[3]; ar[3]=t0; t0=ai[2]; ai[2]=ai[3]; ai[3]=t0; }
        ar[1]=__shfl_xor(ar[1],32); ai[1]=__shfl_xor(ai[1],32);
        ar[3]=__shfl_xor(ar[3],32); ai[3]=__shfl_xor(ai[3],32);
#pragma unroll
        for (int w = 2; w <= 6; ++w) {
            int pc = 7 - w, pt = 6 - w;
            int tm = 1 << pt;
            bool ctrl = (L >> pc) & 1;
#pragma unroll
            for (int r = 0; r < 4; ++r) {
                float swr = __shfl_xor(ar[r], tm);
                float swi = __shfl_xor(ai[r], tm);
                ar[r] = ctrl ? swr : ar[r];
                ai[r] = ctrl ? swi : ai[r];
            }
        }
        {
            bool ctrl = L & 1;
            float n0r = ctrl ? ar[2] : ar[0], n2r = ctrl ? ar[0] : ar[2];
            float n0i = ctrl ? ai[2] : ai[0], n2i = ctrl ? ai[0] : ai[2];
            float n1r = ctrl ? ar[3] : ar[1], n3r = ctrl ? ar[1] : ar[3];
            float n1i = ctrl ? ai[3] : ai[1], n3i = ctrl ? ai[1] : ai[3];
            ar[0]=n0r; ar[1]=n1r; ar[2]=n2r; ar[3]=n3r;
            ai[0]=n0i; ai[1]=n1i; ai[2]=n2i; ai[3]=n3i;
        }
    }

    // ---- <Z_w>, w=0..2 ----
    {
        float p0 = ar[0]*ar[0]+ai[0]*ai[0];
        float p1 = ar[1]*ar[1]+ai[1]*ai[1];
        float p2 = ar[2]*ar[2]+ai[2]*ai[2];
        float p3 = ar[3]*ar[3]+ai[3]*ai[3];
        float z0 = p0 + p1 - p2 - p3;
        float z1 = p0 - p1 + p2 - p3;
        float zs = p0 + p1 + p2 + p3;
        float z2 = (L & 32) ? -zs : zs;
#pragma unroll
        for (int off = 1; off < 64; off <<= 1) {
            z0 += __shfl_xor(z0, off);
            z1 += __shfl_xor(z1, off);
            z2 += __shfl_xor(z2, off);
        }
        if (L == 0) {
            out[b * NC + 0] = z0;
            out[b * NC + 1] = z1;
            out[b * NC + 2] = z2;
        }
    }

    // ---- hand off psi through LDS, redistribute to column layout ----
#pragma unroll
    for (int r = 0; r < 4; ++r) Ps2[(r << 6) | L] = make_float2(ar[r], ai[r]);
    __syncthreads();
    int c   = L >> 2;                 // my column
    int seg = L & 3;                  // my segment (4 elements)
    float gr[4], gi[4];
#pragma unroll
    for (int j = 0; j < 4; ++j) {
        float2 t = Ps2[(seg * 4 + j) * 16 + c];
        gr[j] = t.x; gi[j] = t.y;
    }
    float alm = 0.f;
#pragma unroll
    for (int j = 0; j < 4; ++j) alm += gr[j]*gr[j] + gi[j]*gi[j];
    alm += __shfl_xor(alm, 1);
    alm += __shfl_xor(alm, 2);

    // ---- one-sided Jacobi: XOR tournament, shfl_xor exchange ----
    for (int sweep = 0; sweep < NSWEEP; ++sweep) {
#pragma unroll 1
        for (int m = 1; m <= 15; ++m) {
            int xm = m << 2;          // lane xor mask (column bits)
            float pgr[4], pgi[4];
#pragma unroll
            for (int j = 0; j < 4; ++j) {
                pgr[j] = __shfl_xor(gr[j], xm);
                pgi[j] = __shfl_xor(gi[j], xm);
            }
            float bep = __shfl_xor(alm, xm);   // partner norm (same latency group)
            float d = 0.f, e = 0.f;
#pragma unroll
            for (int j = 0; j < 4; ++j) {
                d += gr[j]*pgr[j] + gi[j]*pgi[j];   // Re(mine^H partner)
                e += gr[j]*pgi[j] - gi[j]*pgr[j];   // Im(mine^H partner)
            }
            d += __shfl_xor(d, 1); e += __shfl_xor(e, 1);
            d += __shfl_xor(d, 2); e += __shfl_xor(e, 2);
            float g2 = d*d + e*e;
            float cth = 1.f, sth = 0.f, cph = 1.f, sph = 0.f, gn = 0.f;
            if (g2 > 1e-26f) {
                gn = sqrtf(g2);
                float ginv = 1.f / gn;
                cph = d * ginv; sph = -e * ginv;    // conj(gamma)/|gamma|
                float tau = (alm - bep) * (0.5f * ginv);
                float t = ((tau >= 0.f) ? 1.f : -1.f) / (fabsf(tau) + sqrtf(1.f + tau*tau));
                cth = rsqrtf(1.f + t*t);
                sth = t * cth;
            }
#pragma unroll
            for (int j = 0; j < 4; ++j) {
                float er = cph*pgr[j] - sph*pgi[j];
                float ei = cph*pgi[j] + sph*pgr[j];
                gr[j] = cth * gr[j] + sth * er;
                gi[j] = cth * gi[j] + sth * ei;
            }
            alm = cth*cth*alm + sth*sth*bep + 2.f*cth*sth*gn;
        }
    }

    float ev = fminf(fmaxf(alm, 1e-10f), 1.0f);
    float term = -ev * logf(ev);
#pragma unroll
    for (int off = 4; off < 64; off <<= 1) term += __shfl_xor(term, off);
    if (L == 0) out[BB * NC + b] = term;
}

extern "C" void kernel_launch(void* const* d_in, const int* in_sizes, int n_in,
                              void* d_out, int out_size, void* d_ws, size_t ws_size,
                              hipStream_t stream) {
    const float* x    = (const float*)d_in[0];
    const float* Wemb = (const float*)d_in[1];
    const float* bemb = (const float*)d_in[2];
    const float* Wq   = (const float*)d_in[3];
    const float* bq   = (const float*)d_in[4];
    const float* Wk   = (const float*)d_in[5];
    const float* bk   = (const float*)d_in[6];
    const float* Wv   = (const float*)d_in[7];
    const float* bv   = (const float*)d_in[8];
    const float* Wo   = (const float*)d_in[9];
    const float* bo   = (const float*)d_in[10];
    const float* ln1g = (const float*)d_in[11];
    const float* ln1b = (const float*)d_in[12];
    const float* ln2g = (const float*)d_in[13];
    const float* ln2b = (const float*)d_in[14];
    const float* Wf1  = (const float*)d_in[15];
    const float* bf1  = (const float*)d_in[16];
    const float* Wf2  = (const float*)d_in[17];
    const float* bf2  = (const float*)d_in[18];
    const float* Wp1  = (const float*)d_in[19];
    const float* bp1  = (const float*)d_in[20];
    const float* Wp2  = (const float*)d_in[21];
    const float* bp2  = (const float*)d_in[22];
    const float* qwts = (const float*)d_in[23];
    float* out = (float*)d_out;

    const size_t M = 1u << 20;           // 1M floats = B*S*D
    float* ws   = (float*)d_ws;
    float* h    = ws;                            // 1M floats
    hf2*   qh   = (hf2*)(ws + M);                // 0.5M floats (BHS*8 halves)
    hf2*   kh   = (hf2*)(ws + M + M / 2);        // 0.5M floats
    hf2*   vt   = (hf2*)(ws + 2 * M);            // 0.5M floats
    float* Ao   = ws + 2 * M + M / 2;            // 1M floats (BHS*8)
    float* pp   = ws + 3 * M + M / 2;            // [16][8][64]

    k_embed<<<BB * SS, 64, 0, stream>>>(x, Wemb, bemb, h);
    for (int l = 0; l < NLAYER; ++l) {
        k_qkv<<<BB * SS / 4, 64, 0, stream>>>(h, Wq, bq, Wk, bk, Wv, bv, qh, kh, vt, l);
        k_attn<<<dim3(BB * HH, 16), 256, 0, stream>>>((const float4*)qh, (const float4*)kh,
                                                      (const float4*)vt, Ao);
        k_mid<<<BB * SS / 4, 128, 0, stream>>>(Ao, Wo, bo, ln1g, ln1b,
                                               Wf1, bf1, Wf2, bf2, ln2g, ln2b, h, l);
    }
    k_pool<<<dim3(BB, 8), 64, 0, stream>>>(h, pp);
    k_tail<<<BB, 64, 0, stream>>>(pp, Wp1, bp1, Wp2, bp2, qwts, out);
}